// Round 1
// baseline (1258.814 us; speedup 1.0000x reference)
//
#include <hip/hip_runtime.h>

// ---------------------------------------------------------------------------
// MusicLSTM: B=256, T=2048, I=2, H=128 (4H=512 gates), P=129 pitches.
// Kernel plan:
//   prep_k : note_W(129x128)+dur_W(1x128) -> f16 weight matrix Wn[144][128] in ws
//   lstm_k : 1 WG (256 thr) per batch elem, persistent loop over t<len[b].
//            Thread tau owns gate rows tau and tau+256 (so pair (j, j+128)
//            holds i,g~  and f,o for column j). W_hh rows in regs as f16x2,
//            h broadcast via LDS (f16), dots via v_dot2_f32_f16.
//            Writes hs[b,t,:] as f16 IN-PLACE into d_out note row bt
//            (128 f16 = 256B fit in the 129*4B row, 16B-aligned start).
//            Writes hT/cT (f32) at end.
//   proj_k : MFMA f16 16x16x32 GEMM, 1 wave per 16 output rows, N=144
//            (cols 0..128 = note, 129 = duration, 130..143 discarded).
//            Reads its own hs rows before overwriting them (race-free).
//            Rows with t>=len[b] are written as exact zeros.
// ---------------------------------------------------------------------------

typedef _Float16 f16;
typedef _Float16 f16x2 __attribute__((ext_vector_type(2)));
typedef _Float16 f16x8 __attribute__((ext_vector_type(8)));
typedef float    f32x4 __attribute__((ext_vector_type(4)));

#define B_  256
#define T_  2048
#define H_  128
#define G_  512
#define P_  129

static constexpr size_t NOTE_N   = (size_t)B_ * T_ * P_;        // 67,633,152
static constexpr size_t DUR_BASE = NOTE_N;                      // + B*T
static constexpr size_t HT_BASE  = DUR_BASE + (size_t)B_ * T_;  // + B*H
static constexpr size_t CT_BASE  = HT_BASE + (size_t)B_ * H_;

#if defined(__has_builtin)
#if __has_builtin(__builtin_amdgcn_fdot2)
#define HAVE_FDOT2 1
#endif
#endif

__device__ __forceinline__ float dot2_acc(f16x2 a, f16x2 b, float c) {
#ifdef HAVE_FDOT2
    return __builtin_amdgcn_fdot2(a, b, c, false);
#else
    return c + (float)a[0] * (float)b[0] + (float)a[1] * (float)b[1];
#endif
}

__device__ __forceinline__ float fast_rcp(float x) { return __builtin_amdgcn_rcpf(x); }

__device__ __forceinline__ float sigmoid_f(float x) {
    x = fminf(fmaxf(x, -30.f), 30.f);
    float e = __expf(-x);
    return fast_rcp(1.f + e);
}
__device__ __forceinline__ float tanh_f(float x) {
    x = fminf(fmaxf(x, -15.f), 15.f);
    float e = __expf(2.f * x);
    return (e - 1.f) * fast_rcp(e + 1.f);
}

// hs row bt lives at the front of note row bt, rounded up to 16B alignment.
// Row data = 128 f16 = 256 B; 256+12 < 516 B (=129 floats) so it fits.
__device__ __forceinline__ f16* hs_row(float* out, int bt) {
    size_t byteoff = ((size_t)bt * (P_ * 4) + 15) & ~(size_t)15;
    return (f16*)((char*)out + byteoff);
}

// ---------------------------------------------------------------------------
__global__ __launch_bounds__(256) void prep_k(const float* __restrict__ note_W,
                                              const float* __restrict__ dur_W,
                                              f16* __restrict__ Wn) {
    int i = threadIdx.x + blockIdx.x * 256;  // 144*128 = 18432 elements
    if (i >= 144 * 128) return;
    int row = i >> 7, k = i & 127;
    float v = 0.f;
    if (row < 129)       v = note_W[row * 128 + k];
    else if (row == 129) v = dur_W[k];
    Wn[i] = (f16)v;
}

// ---------------------------------------------------------------------------
__global__ __launch_bounds__(256) void lstm_k(const float* __restrict__ x,
                                              const int* __restrict__ lengths,
                                              const float* __restrict__ W_ih,
                                              const float* __restrict__ W_hh,
                                              float* __restrict__ out) {
    __shared__ float2 xs[T_];                 // 16 KB: this batch's inputs
    __shared__ float g_sh[G_];                // activated gates
    __shared__ __align__(16) f16 h_sh[H_];    // h broadcast (f16)

    const int tid = threadIdx.x;
    const int b = blockIdx.x;
    const int row0 = tid, row1 = tid + 256;

    // W_hh rows for this thread's two gates, packed f16x2 in registers.
    f16x2 w0[64], w1[64];
    {
        const float4* r0 = (const float4*)(W_hh + (size_t)row0 * H_);
        const float4* r1 = (const float4*)(W_hh + (size_t)row1 * H_);
#pragma unroll
        for (int q = 0; q < 32; q++) {
            float4 v = r0[q];
            f16x2 p; p[0] = (f16)v.x; p[1] = (f16)v.y; w0[2 * q] = p;
            f16x2 s; s[0] = (f16)v.z; s[1] = (f16)v.w; w0[2 * q + 1] = s;
            float4 u = r1[q];
            f16x2 p1; p1[0] = (f16)u.x; p1[1] = (f16)u.y; w1[2 * q] = p1;
            f16x2 s1; s1[0] = (f16)u.z; s1[1] = (f16)u.w; w1[2 * q + 1] = s1;
        }
    }
    const float wi0x = W_ih[2 * row0], wi0y = W_ih[2 * row0 + 1];
    const float wi1x = W_ih[2 * row1], wi1y = W_ih[2 * row1 + 1];

    // stage x[b,:,:] into LDS
    const float2* xg = (const float2*)(x + (size_t)b * T_ * 2);
    for (int i = tid; i < T_; i += 256) xs[i] = xg[i];
    if (tid < H_) h_sh[tid] = (f16)0.f;

    const int len = lengths[b];
    float c_reg = 0.f, h_reg = 0.f;
    __syncthreads();

    for (int t = 0; t < len; t++) {
        float2 xt = xs[t];
        float acc0a = wi0x * xt.x + wi0y * xt.y;   // pre-projection (exact f32)
        float acc1a = wi1x * xt.x + wi1y * xt.y;
        float acc0b = 0.f, acc1b = 0.f;
        const f16x8* hv = (const f16x8*)h_sh;
#pragma unroll
        for (int kk = 0; kk < 16; kk++) {
            f16x8 hh = hv[kk];
            f16x2 h0; h0[0] = hh[0]; h0[1] = hh[1];
            f16x2 h1; h1[0] = hh[2]; h1[1] = hh[3];
            f16x2 h2; h2[0] = hh[4]; h2[1] = hh[5];
            f16x2 h3; h3[0] = hh[6]; h3[1] = hh[7];
            acc0a = dot2_acc(w0[4 * kk + 0], h0, acc0a);
            acc0b = dot2_acc(w0[4 * kk + 1], h1, acc0b);
            acc1a = dot2_acc(w1[4 * kk + 0], h0, acc1a);
            acc1b = dot2_acc(w1[4 * kk + 1], h1, acc1b);
            acc0a = dot2_acc(w0[4 * kk + 2], h2, acc0a);
            acc0b = dot2_acc(w0[4 * kk + 3], h3, acc0b);
            acc1a = dot2_acc(w1[4 * kk + 2], h2, acc1a);
            acc1b = dot2_acc(w1[4 * kk + 3], h3, acc1b);
        }
        float d0 = acc0a + acc0b;     // gate row tau   (i or f)  -> sigmoid
        float d1 = acc1a + acc1b;     // gate row tau+256 (g~ or o)
        float act0 = sigmoid_f(d0);
        // tanh(x) = 2*sigmoid(2x)-1 : branchless shared path
        float s = (tid < 128) ? 2.f : 1.f;
        float sg = sigmoid_f(d1 * s);
        float act1 = sg * s - (s - 1.f);

        g_sh[row0] = act0;
        g_sh[row1] = act1;
        __syncthreads();   // gates visible; all h_sh reads of this step done

        if (tid < H_) {
            float ig = g_sh[tid];
            float fg = g_sh[tid + 128];
            float gg = g_sh[tid + 256];
            float og = g_sh[tid + 384];
            c_reg = fg * c_reg + ig * gg;
            float tc = tanh_f(c_reg);
            h_reg = og * tc;
            h_sh[tid] = (f16)h_reg;
            hs_row(out, b * T_ + t)[tid] = (f16)h_reg;
        }
        __syncthreads();   // new h visible before next step's dots
    }

    if (tid < H_) {
        out[HT_BASE + (size_t)b * H_ + tid] = h_reg;
        out[CT_BASE + (size_t)b * H_ + tid] = c_reg;
    }
}

// ---------------------------------------------------------------------------
// Projection GEMM: C[bt, n] = hs[bt,:] . Wn[n,:] + bias, masked by t<len.
// 1 wave per 16-row M-tile; 4 waves/WG -> 64 rows/WG; 8192 WGs.
__global__ __launch_bounds__(256) void proj_k(const int* __restrict__ lengths,
                                              const f16* __restrict__ Wn,
                                              const float* __restrict__ note_b,
                                              const float* __restrict__ dur_b,
                                              float* __restrict__ out) {
    // Wn staged in LDS with padded row stride (136 halves = 68 words) to
    // spread MFMA B-fragment reads across banks.
    __shared__ __align__(16) f16 wn_sh[144 * 136];

    const int tid = threadIdx.x;
    {
        unsigned int* dst = (unsigned int*)wn_sh;
        const unsigned int* src = (const unsigned int*)Wn;
        for (int w = tid; w < 144 * 64; w += 256) {
            int row = w >> 6, cw = w & 63;
            dst[row * 68 + cw] = src[w];
        }
    }
    __syncthreads();

    const int wv = tid >> 6;
    const int l = tid & 63;
    const int tile = blockIdx.x * 4 + wv;   // 16-row tile
    const int bt0 = tile * 16;
    const int b = bt0 >> 11;                // T=2048
    const int t0 = bt0 & 2047;
    const int len = lengths[b];
    const int r16 = l & 15, q = l >> 4;

    f32x4 acc[9];
#pragma unroll
    for (int nf = 0; nf < 9; nf++) acc[nf] = f32x4{0.f, 0.f, 0.f, 0.f};

    const bool live = (t0 < len);
    if (live) {
        f16x8 a[4];
        {
            const f16* ar = hs_row(out, bt0 + r16);
#pragma unroll
            for (int kk = 0; kk < 4; kk++)
                a[kk] = *(const f16x8*)(ar + kk * 32 + q * 8);
        }
#pragma unroll
        for (int nf = 0; nf < 9; nf++) {
            const f16* brow = wn_sh + (nf * 16 + r16) * 136 + q * 8;
#pragma unroll
            for (int kk = 0; kk < 4; kk++) {
                f16x8 bb = *(const f16x8*)(brow + kk * 32);
                acc[nf] = __builtin_amdgcn_mfma_f32_16x16x32_f16(a[kk], bb, acc[nf], 0, 0, 0);
            }
        }
    }

    // epilogue: C row = bt0 + q*4 + r, col = nf*16 + r16
#pragma unroll
    for (int nf = 0; nf < 9; nf++) {
        int col = nf * 16 + r16;
        float bias = 0.f;
        if (col < 129)       bias = note_b[col];
        else if (col == 129) bias = dur_b[0];
#pragma unroll
        for (int r = 0; r < 4; r++) {
            int rowbt = bt0 + q * 4 + r;
            int t = t0 + q * 4 + r;
            float v = (t < len) ? (acc[nf][r] + bias) : 0.f;
            if (col < 129)
                out[(size_t)rowbt * P_ + col] = v;
            else if (col == 129)
                out[DUR_BASE + rowbt] = v;
        }
    }
}

// ---------------------------------------------------------------------------
extern "C" void kernel_launch(void* const* d_in, const int* in_sizes, int n_in,
                              void* d_out, int out_size, void* d_ws, size_t ws_size,
                              hipStream_t stream) {
    const float* x       = (const float*)d_in[0];
    const int*   lengths = (const int*)d_in[1];
    const float* W_ih    = (const float*)d_in[2];
    const float* W_hh    = (const float*)d_in[3];
    const float* note_W  = (const float*)d_in[4];
    const float* note_b  = (const float*)d_in[5];
    const float* dur_W   = (const float*)d_in[6];
    const float* dur_b   = (const float*)d_in[7];
    float* out = (float*)d_out;
    f16* Wn = (f16*)d_ws;   // 144*128*2 = 36,864 bytes

    prep_k<<<72, 256, 0, stream>>>(note_W, dur_W, Wn);
    lstm_k<<<B_, 256, 0, stream>>>(x, lengths, W_ih, W_hh, out);
    proj_k<<<(B_ * T_) / 64, 256, 0, stream>>>(lengths, Wn, note_b, dur_b, out);
}

// Round 4
// 1250.131 us; speedup vs baseline: 1.0069x; 1.0069x over previous
//
#include <hip/hip_runtime.h>

// ---------------------------------------------------------------------------
// MusicLSTM: B=256, T=2048, I=2, H=128 (4H=512 gates), P=129 pitches.
//   prep_k : note_W(129x128)+dur_W(1x128) -> f16 weight matrix Wn[144][128] in ws
//   lstm_k : 1 WG (512 thr) per batch elem. Thread (col=tid>>2, kq=tid&3)
//            computes ALL 4 gates of column col over K-quarter kq (64 dot2),
//            cross-K reduce via 2 DPP quad shuffles (no LDS), input projection
//            added AFTER the reduce (it is lane-redundant, adding it before
//            the reduce counts it 4x -- that was round 3's bug), cell update
//            redundant in all lanes, ONE barrier/step, double-buffered h.
//            Writes hs[b,t,:] f16 in-place into d_out note row bt.
//   proj_k : MFMA f16 16x16x32 GEMM over hs, N=144 (129 note + 1 dur + pad),
//            masked rows written as exact zeros.
// ---------------------------------------------------------------------------

typedef _Float16 f16;
typedef _Float16 f16x2 __attribute__((ext_vector_type(2)));
typedef _Float16 f16x8 __attribute__((ext_vector_type(8)));
typedef float    f32x4 __attribute__((ext_vector_type(4)));

#define B_  256
#define T_  2048
#define H_  128
#define P_  129

static constexpr size_t NOTE_N   = (size_t)B_ * T_ * P_;
static constexpr size_t DUR_BASE = NOTE_N;
static constexpr size_t HT_BASE  = DUR_BASE + (size_t)B_ * T_;
static constexpr size_t CT_BASE  = HT_BASE + (size_t)B_ * H_;

#if defined(__has_builtin)
#if __has_builtin(__builtin_amdgcn_fdot2)
#define HAVE_FDOT2 1
#endif
#if __has_builtin(__builtin_amdgcn_exp2f)
#define EXP2F(x) __builtin_amdgcn_exp2f(x)
#endif
#if __has_builtin(__builtin_amdgcn_mov_dpp)
#define HAVE_DPP 1
#endif
#endif
#ifndef EXP2F
#define EXP2F(x) __expf((x) * 0.6931471805599453f)
#endif

__device__ __forceinline__ float dot2_acc(f16x2 a, f16x2 b, float c) {
#ifdef HAVE_FDOT2
    return __builtin_amdgcn_fdot2(a, b, c, false);
#else
    return c + (float)a[0] * (float)b[0] + (float)a[1] * (float)b[1];
#endif
}

__device__ __forceinline__ float fast_rcp(float x) { return __builtin_amdgcn_rcpf(x); }

__device__ __forceinline__ float sigmoid_f(float x) {
    float e = EXP2F(-1.44269504f * x);
    return fast_rcp(1.f + e);
}
// tanh for |x| <~ 15 (no overflow: exp2(2.885*15)=2^43)
__device__ __forceinline__ float tanh_f(float x) {
    float e = EXP2F(2.885390082f * x);
    return (e - 1.f) * fast_rcp(e + 1.f);
}

// quad all-reduce sum (lanes differing in bits 0-1) via DPP quad_perm
__device__ __forceinline__ float quad_allsum(float v) {
#ifdef HAVE_DPP
    int a = __float_as_int(v);
    v += __int_as_float(__builtin_amdgcn_mov_dpp(a, 0xB1, 0xF, 0xF, true)); // xor 1
    a = __float_as_int(v);
    v += __int_as_float(__builtin_amdgcn_mov_dpp(a, 0x4E, 0xF, 0xF, true)); // xor 2
    return v;
#else
    v += __shfl_xor(v, 1, 64);
    v += __shfl_xor(v, 2, 64);
    return v;
#endif
}

// hs row bt lives at the front of note row bt, rounded up to 16B alignment.
__device__ __forceinline__ f16* hs_row(float* out, int bt) {
    size_t byteoff = ((size_t)bt * (P_ * 4) + 15) & ~(size_t)15;
    return (f16*)((char*)out + byteoff);
}

// ---------------------------------------------------------------------------
__global__ __launch_bounds__(256) void prep_k(const float* __restrict__ note_W,
                                              const float* __restrict__ dur_W,
                                              f16* __restrict__ Wn) {
    int i = threadIdx.x + blockIdx.x * 256;
    if (i >= 144 * 128) return;
    int row = i >> 7, k = i & 127;
    float v = 0.f;
    if (row < 129)       v = note_W[row * 128 + k];
    else if (row == 129) v = dur_W[k];
    Wn[i] = (f16)v;
}

// ---------------------------------------------------------------------------
__global__ __launch_bounds__(512) void lstm_k(const float* __restrict__ x,
                                              const int* __restrict__ lengths,
                                              const float* __restrict__ W_ih,
                                              const float* __restrict__ W_hh,
                                              float* __restrict__ out) {
    __shared__ float2 xs[T_];                       // 16 KB
    __shared__ __align__(16) f16 h_sh[2][H_];       // double-buffered h

    const int tid = threadIdx.x;
    const int b = blockIdx.x;
    const int col = tid >> 2;       // 0..127 : hidden column
    const int kq  = tid & 3;        // K-quarter: elems [kq*32, kq*32+32)

    // Per-thread weights: 4 gate rows (i,f,g,o = col + g*128), K-slice of 32.
    f16x2 wg[4][16];
    float wix[4], wiy[4];
#pragma unroll
    for (int g = 0; g < 4; g++) {
        const int row = col + g * H_;
        const float4* src = (const float4*)(W_hh + (size_t)row * H_ + kq * 32);
#pragma unroll
        for (int q = 0; q < 8; q++) {
            float4 v = src[q];
            f16x2 p; p[0] = (f16)v.x; p[1] = (f16)v.y; wg[g][2 * q] = p;
            f16x2 s; s[0] = (f16)v.z; s[1] = (f16)v.w; wg[g][2 * q + 1] = s;
        }
        wix[g] = W_ih[2 * row];
        wiy[g] = W_ih[2 * row + 1];
    }

    // stage x[b,:,:] into LDS; zero both h buffers
    const float2* xg = (const float2*)(x + (size_t)b * T_ * 2);
    for (int i = tid; i < T_; i += 512) xs[i] = xg[i];
    if (tid < 2 * H_) ((f16*)h_sh)[tid] = (f16)0.f;

    const int len = lengths[b];
    float c_reg = 0.f, h_out = 0.f;
    __syncthreads();

    for (int t = 0; t < len; t++) {
        const float2 xt = xs[t];
        // read this thread's h K-slice (64B, broadcast across cols)
        union { f16x8 v8[4]; f16x2 v2[16]; } hu;
        {
            const f16x8* hv = (const f16x8*)(h_sh[t & 1] + (kq << 5));
#pragma unroll
            for (int q = 0; q < 4; q++) hu.v8[q] = hv[q];
        }

        // partial dots over this lane's K-quarter (input proj added AFTER reduce)
        float a0 = 0.f, a1 = 0.f, a2 = 0.f, a3 = 0.f;
#pragma unroll
        for (int idx = 0; idx < 16; idx++) {
            f16x2 hp = hu.v2[idx];
            a0 = dot2_acc(wg[0][idx], hp, a0);
            a1 = dot2_acc(wg[1][idx], hp, a1);
            a2 = dot2_acc(wg[2][idx], hp, a2);
            a3 = dot2_acc(wg[3][idx], hp, a3);
        }
        // full gate sums in every lane of the quad
        a0 = quad_allsum(a0);
        a1 = quad_allsum(a1);
        a2 = quad_allsum(a2);
        a3 = quad_allsum(a3);
        // input projection: identical in all 4 lanes -> add once, post-reduce
        a0 += __builtin_fmaf(wiy[0], xt.y, wix[0] * xt.x);
        a1 += __builtin_fmaf(wiy[1], xt.y, wix[1] * xt.x);
        a2 += __builtin_fmaf(wiy[2], xt.y, wix[2] * xt.x);
        a3 += __builtin_fmaf(wiy[3], xt.y, wix[3] * xt.x);

        const float ig = sigmoid_f(a0);
        const float fg = sigmoid_f(a1);
        const float gg = tanh_f(a2);
        const float og = sigmoid_f(a3);
        c_reg = __builtin_fmaf(fg, c_reg, ig * gg);
        const float cc = fminf(fmaxf(c_reg, -15.f), 15.f);
        h_out = og * tanh_f(cc);

        if (kq == 0) {
            const f16 h16 = (f16)h_out;
            h_sh[(t & 1) ^ 1][col] = h16;
            hs_row(out, b * T_ + t)[col] = h16;
        }
        __syncthreads();   // new h visible; also guards WAR on the buffer
    }

    if (kq == 0) {
        out[HT_BASE + (size_t)b * H_ + col] = h_out;
        out[CT_BASE + (size_t)b * H_ + col] = c_reg;
    }
}

// ---------------------------------------------------------------------------
// Projection GEMM: C[bt, n] = hs[bt,:] . Wn[n,:] + bias, masked by t<len.
__global__ __launch_bounds__(256) void proj_k(const int* __restrict__ lengths,
                                              const f16* __restrict__ Wn,
                                              const float* __restrict__ note_b,
                                              const float* __restrict__ dur_b,
                                              float* __restrict__ out) {
    __shared__ __align__(16) f16 wn_sh[144 * 136];

    const int tid = threadIdx.x;
    {
        unsigned int* dst = (unsigned int*)wn_sh;
        const unsigned int* src = (const unsigned int*)Wn;
        for (int w = tid; w < 144 * 64; w += 256) {
            int row = w >> 6, cw = w & 63;
            dst[row * 68 + cw] = src[w];
        }
    }
    __syncthreads();

    const int wv = tid >> 6;
    const int l = tid & 63;
    const int tile = blockIdx.x * 4 + wv;
    const int bt0 = tile * 16;
    const int b = bt0 >> 11;
    const int t0 = bt0 & 2047;
    const int len = lengths[b];
    const int r16 = l & 15, q = l >> 4;

    f32x4 acc[9];
#pragma unroll
    for (int nf = 0; nf < 9; nf++) acc[nf] = f32x4{0.f, 0.f, 0.f, 0.f};

    const bool live = (t0 < len);
    if (live) {
        f16x8 a[4];
        {
            const f16* ar = hs_row(out, bt0 + r16);
#pragma unroll
            for (int kk = 0; kk < 4; kk++)
                a[kk] = *(const f16x8*)(ar + kk * 32 + q * 8);
        }
#pragma unroll
        for (int nf = 0; nf < 9; nf++) {
            const f16* brow = wn_sh + (nf * 16 + r16) * 136 + q * 8;
#pragma unroll
            for (int kk = 0; kk < 4; kk++) {
                f16x8 bb = *(const f16x8*)(brow + kk * 32);
                acc[nf] = __builtin_amdgcn_mfma_f32_16x16x32_f16(a[kk], bb, acc[nf], 0, 0, 0);
            }
        }
    }

#pragma unroll
    for (int nf = 0; nf < 9; nf++) {
        int col = nf * 16 + r16;
        float bias = 0.f;
        if (col < 129)       bias = note_b[col];
        else if (col == 129) bias = dur_b[0];
#pragma unroll
        for (int r = 0; r < 4; r++) {
            int rowbt = bt0 + q * 4 + r;
            int t = t0 + q * 4 + r;
            float v = (t < len) ? (acc[nf][r] + bias) : 0.f;
            if (col < 129)
                out[(size_t)rowbt * P_ + col] = v;
            else if (col == 129)
                out[DUR_BASE + rowbt] = v;
        }
    }
}

// ---------------------------------------------------------------------------
extern "C" void kernel_launch(void* const* d_in, const int* in_sizes, int n_in,
                              void* d_out, int out_size, void* d_ws, size_t ws_size,
                              hipStream_t stream) {
    const float* x       = (const float*)d_in[0];
    const int*   lengths = (const int*)d_in[1];
    const float* W_ih    = (const float*)d_in[2];
    const float* W_hh    = (const float*)d_in[3];
    const float* note_W  = (const float*)d_in[4];
    const float* note_b  = (const float*)d_in[5];
    const float* dur_W   = (const float*)d_in[6];
    const float* dur_b   = (const float*)d_in[7];
    float* out = (float*)d_out;
    f16* Wn = (f16*)d_ws;

    prep_k<<<72, 256, 0, stream>>>(note_W, dur_W, Wn);
    lstm_k<<<B_, 512, 0, stream>>>(x, lengths, W_ih, W_hh, out);
    proj_k<<<(B_ * T_) / 64, 256, 0, stream>>>(lengths, Wn, note_b, dur_b, out);
}